// Round 8
// baseline (218.537 us; speedup 1.0000x reference)
//
#include <hip/hip_runtime.h>
#include <stdint.h>

// ODE sampler (VP-SDE probability-flow, RK4, T=50) for B=2048, D=16, H=256.
// tr(J) analytic: tr = -0.5*beta*(D + sum_k (1-h_k^2)*c_k).
//
// R8: R6's winning f16-fdot2 base (125us kernel, VALUBusy 72% @ 2 waves/SIMD),
// restructured as TWO waves per sample with a k-split in BOTH phases:
//  - wave W owns k in [128W, 128W+128): phase-1 = 2 k/lane (16 fdot2, 2 tanh);
//    phase-2 = all 16 outputs dotted over the wave's OWN 128 h (16 fdot2)
//    -> no work duplication, h write->read stays same-wave (in-order DS pipe,
//    no barrier), cross-wave traffic = 16 partial scores only.
//  - partial-score exchange: double-buffered LDS + ONE 2-wave barrier/Feval.
//  - grid 2048 x 128thr -> 8 blocks/CU = 4 waves/SIMD (2x R6's TLP).
//  - kept from R6: readlane x-broadcast, DPP reductions, exp2-prescaled tanh,
//    deferred per-lane ldj. (R7 disproved the pk_fma_f32 path: fdot2 wins.)

typedef _Float16 f16x2 __attribute__((ext_vector_type(2)));

#if defined(__has_builtin)
#if __has_builtin(__builtin_amdgcn_fdot2)
#define HAVE_FDOT2 1
#endif
#endif

__device__ __forceinline__ float fdot2f(f16x2 a, f16x2 b, float c) {
#ifdef HAVE_FDOT2
    return __builtin_amdgcn_fdot2(a, b, c, false);
#else
    return fmaf((float)a.y, (float)b.y, fmaf((float)a.x, (float)b.x, c));
#endif
}

__device__ __forceinline__ uint32_t pk(float a, float b) {
    f16x2 v; v.x = (_Float16)a; v.y = (_Float16)b;   // RNE casts
    return __builtin_bit_cast(uint32_t, v);
}
__device__ __forceinline__ f16x2 upk(uint32_t u) {
    return __builtin_bit_cast(f16x2, u);
}

// DPP add over the low-3 bits of lane id (8-lane groups); VALU pipe.
#define DPP_X1  0xB1    // quad_perm [1,0,3,2]  (^1)
#define DPP_X2  0x4E    // quad_perm [2,3,0,1]  (^2)
#define DPP_HM  0x141   // row_half_mirror      (quad<->quad within 8)
template <int CTRL>
__device__ __forceinline__ float dpp_add(float x) {
    const int xi = __builtin_bit_cast(int, x);
    const int v  = __builtin_amdgcn_update_dpp(xi, xi, CTRL, 0xF, 0xF, false);
    return x + __builtin_bit_cast(float, v);
}

#define Bn 2048
#define Dn 16
#define Hn 256
#define Tn 50

__global__ __launch_bounds__(128, 4) void ode_kernel(
    const float* __restrict__ x_in,   // [B][D]
    const float* __restrict__ W1,     // [D][H]
    const float* __restrict__ b1v,    // [H]
    const float* __restrict__ wtv,    // [H]
    const float* __restrict__ W2,     // [H][D]
    const float* __restrict__ b2v,    // [D]
    float* __restrict__ out)          // xf[B*D] | ldjf[B] | xt[T*B*D]
{
    __shared__ uint32_t h_lds[128];        // 2 waves x 64 dwords (f16-pair h)
    __shared__ float    sc_buf[2][2][16];  // [parity][wave][i] partial scores
    __shared__ float    ldj_buf[2];

    const int t  = threadIdx.x;
    const int W  = t >> 6;            // wave 0/1 (k-half owner)
    const int L  = t & 63;
    const int g8 = L >> 3;            // i-pair group 0..7
    const int c  = L & 7;             // phase-2 k-chunk (16 k) within own half
    const int ia = 2 * g8, ib = ia + 1;
    const int kp = 64 * W + L;        // h-pair id: k = 2kp, 2kp+1
    const int gs = blockIdx.x;        // one sample per block

    const float K2 = 2.88539008f;     // 2*log2(e): exp2(K2*u) = e^{2u}

    // ---- one-time init: weights packed to f16 registers ----
    f16x2 w1p[2][8];                  // [q][j] = K2*{W1[2j][2kp+q], W1[2j+1][2kp+q]}
    float b1k[2], wtk[2], ck[2];
    #pragma unroll
    for (int q = 0; q < 2; ++q) {
        const int k = 2 * kp + q;
        #pragma unroll
        for (int j = 0; j < 8; ++j) {
            f16x2 v;
            v.x = (_Float16)(K2 * W1[(2 * j)     * Hn + k]);
            v.y = (_Float16)(K2 * W1[(2 * j + 1) * Hn + k]);
            w1p[q][j] = v;
        }
        b1k[q] = K2 * b1v[k];
        wtk[q] = K2 * wtv[k];
        float s = 0.f;                // c_k from original f32 weights
        #pragma unroll
        for (int ii = 0; ii < 16; ++ii)
            s = fmaf(W1[ii * Hn + k], W2[k * Dn + ii], s);
        ck[q] = s;
    }
    f16x2 w2a[8], w2b[8];             // 16 k of own half for outputs ia/ib
    #pragma unroll
    for (int m = 0; m < 8; ++m) {
        const int kk = 128 * W + 16 * c + 2 * m;
        f16x2 va, vb;
        va.x = (_Float16)W2[kk * Dn + ia];  va.y = (_Float16)W2[(kk + 1) * Dn + ia];
        vb.x = (_Float16)W2[kk * Dn + ib];  vb.y = (_Float16)W2[(kk + 1) * Dn + ib];
        w2a[m] = va; w2b[m] = vb;
    }
    const float b2a = b2v[ia], b2b = b2v[ib];

    // lane state (replicated across c-lanes and across both waves)
    float xa = x_in[gs * Dn + ia];
    float xb = x_in[gs * Dn + ib];
    float ldjl = 0.f, wbsum = 0.f;

    float* xf_out  = out;
    float* ldj_out = out + (size_t)Bn * Dn;
    float* xt_ptr  = out + (size_t)Bn * Dn + Bn + gs * Dn + ia;

    if (W == 0 && c == 0) *(float2*)xt_ptr = make_float2(xa, xb);   // xt[0]
    xt_ptr += Bn * Dn;

    const int hwr = 64 * W + L;       // h write slot (dword, stride-1)
    const int hrd = 64 * W + 8 * c;   // h read base (2 x b128, own half)

    // x-broadcast: 8 readlanes -> wave-uniform packed f16 pairs
    uint32_t se0, se1, se2, se3, se4, se5, se6, se7;
    auto bcast = [&](float ea, float eb) {
        const uint32_t vpk = pk(ea, eb);      // lane 8j holds pair (2j, 2j+1)
        se0 = __builtin_amdgcn_readlane(vpk,  0);
        se1 = __builtin_amdgcn_readlane(vpk,  8);
        se2 = __builtin_amdgcn_readlane(vpk, 16);
        se3 = __builtin_amdgcn_readlane(vpk, 24);
        se4 = __builtin_amdgcn_readlane(vpk, 32);
        se5 = __builtin_amdgcn_readlane(vpk, 40);
        se6 = __builtin_amdgcn_readlane(vpk, 48);
        se7 = __builtin_amdgcn_readlane(vpk, 56);
    };

    int fe = 0;                       // Feval counter (parity for sc_buf)

    auto Feval = [&](float xeva, float xevb, float tt, float wgt,
                     float& dxa, float& dxb) {
        const int p = fe & 1; ++fe;

        // ---- phase 1: this lane's 2 hidden units (own k-half) ----
        float u0 = fmaf(tt, wtk[0], b1k[0]);
        float u1 = fmaf(tt, wtk[1], b1k[1]);
        {
            const f16x2 xp0 = upk(se0), xp1 = upk(se1), xp2 = upk(se2), xp3 = upk(se3);
            const f16x2 xp4 = upk(se4), xp5 = upk(se5), xp6 = upk(se6), xp7 = upk(se7);
            u0 = fdot2f(xp0, w1p[0][0], u0);  u1 = fdot2f(xp0, w1p[1][0], u1);
            u0 = fdot2f(xp1, w1p[0][1], u0);  u1 = fdot2f(xp1, w1p[1][1], u1);
            u0 = fdot2f(xp2, w1p[0][2], u0);  u1 = fdot2f(xp2, w1p[1][2], u1);
            u0 = fdot2f(xp3, w1p[0][3], u0);  u1 = fdot2f(xp3, w1p[1][3], u1);
            u0 = fdot2f(xp4, w1p[0][4], u0);  u1 = fdot2f(xp4, w1p[1][4], u1);
            u0 = fdot2f(xp5, w1p[0][5], u0);  u1 = fdot2f(xp5, w1p[1][5], u1);
            u0 = fdot2f(xp6, w1p[0][6], u0);  u1 = fdot2f(xp6, w1p[1][6], u1);
            u0 = fdot2f(xp7, w1p[0][7], u0);  u1 = fdot2f(xp7, w1p[1][7], u1);
        }
        // prescaled: exp2(u)=e^{2u_true}; tanh = 1 - 2/(E+1), saturation exact
        const float h0 = fmaf(-2.f, __builtin_amdgcn_rcpf(__builtin_amdgcn_exp2f(u0) + 1.f), 1.f);
        const float h1 = fmaf(-2.f, __builtin_amdgcn_rcpf(__builtin_amdgcn_exp2f(u1) + 1.f), 1.f);
        h_lds[hwr] = pk(h0, h1);

        // trace partial + deferred ldj (fills the DS write->read bubble)
        const float gl   = fmaf(-h0 * h0, ck[0], ck[0]) + fmaf(-h1 * h1, ck[1], ck[1]);
        const float beta = fmaf(tt, 19.9f, 0.1f);
        const float nhb  = -0.5f * beta;
        const float wb   = wgt * nhb;
        ldjl  = fmaf(wb, gl, ldjl);
        wbsum += wb;

        asm volatile("" ::: "memory");     // same-wave DS order: write < reads

        // ---- phase 2: outputs (ia,ib) over own 16-k chunk ----
        const uint4 hv0 = *(const uint4*)&h_lds[hrd];
        const uint4 hv1 = *(const uint4*)&h_lds[hrd + 4];
        const f16x2 p0 = upk(hv0.x), p1 = upk(hv0.y), p2 = upk(hv0.z), p3 = upk(hv0.w);
        const f16x2 p4 = upk(hv1.x), p5 = upk(hv1.y), p6 = upk(hv1.z), p7 = upk(hv1.w);
        float sa = 0.f, sb = 0.f;
        sa = fdot2f(p0, w2a[0], sa);  sb = fdot2f(p0, w2b[0], sb);
        sa = fdot2f(p1, w2a[1], sa);  sb = fdot2f(p1, w2b[1], sb);
        sa = fdot2f(p2, w2a[2], sa);  sb = fdot2f(p2, w2b[2], sb);
        sa = fdot2f(p3, w2a[3], sa);  sb = fdot2f(p3, w2b[3], sb);
        sa = fdot2f(p4, w2a[4], sa);  sb = fdot2f(p4, w2b[4], sb);
        sa = fdot2f(p5, w2a[5], sa);  sb = fdot2f(p5, w2b[5], sb);
        sa = fdot2f(p6, w2a[6], sa);  sb = fdot2f(p6, w2b[6], sb);
        sa = fdot2f(p7, w2a[7], sa);  sb = fdot2f(p7, w2b[7], sb);
        // 8-lane reduce on VALU (own k-half partial)
        sa = dpp_add<DPP_X1>(sa);  sb = dpp_add<DPP_X1>(sb);
        sa = dpp_add<DPP_X2>(sa);  sb = dpp_add<DPP_X2>(sb);
        sa = dpp_add<DPP_HM>(sa);  sb = dpp_add<DPP_HM>(sb);

        // ---- cross-wave partial exchange (double-buffered, 1 barrier) ----
        if (c < 2) sc_buf[p][W][ia + c] = (c == 0) ? sa : sb;
        __syncthreads();
        const float2 o = *(const float2*)&sc_buf[p][1 - W][ia];

        dxa = nhb * (xeva + sa + o.x + b2a);
        dxb = nhb * (xevb + sb + o.y + b2b);
    };

    const float t_lo = 1e-3f;
    const float dt   = (1.0f - 1e-3f) / (float)(Tn - 1);
    const float hh   = dt;
    const float w1w  = hh * (1.f / 6.f);
    const float w2w  = hh * (2.f / 6.f);

    bcast(xa, xb);
    for (int j = 0; j < Tn - 1; ++j) {
        const float t0 = fmaf((float)j, dt, t_lo);
        const float tm = t0 + 0.5f * hh;
        const float t1 = t0 + hh;
        float k1a, k1b, k2a, k2b, k3a, k3b, k4a, k4b;

        Feval(xa, xb, t0, w1w, k1a, k1b);
        const float e2a = fmaf(0.5f * hh, k1a, xa);
        const float e2b = fmaf(0.5f * hh, k1b, xb);
        bcast(e2a, e2b);
        Feval(e2a, e2b, tm, w2w, k2a, k2b);
        const float e3a = fmaf(0.5f * hh, k2a, xa);
        const float e3b = fmaf(0.5f * hh, k2b, xb);
        bcast(e3a, e3b);
        Feval(e3a, e3b, tm, w2w, k3a, k3b);
        const float e4a = fmaf(hh, k3a, xa);
        const float e4b = fmaf(hh, k3b, xb);
        bcast(e4a, e4b);
        Feval(e4a, e4b, t1, w1w, k4a, k4b);

        xa = fmaf(w1w, k1a + 2.f * (k2a + k3a) + k4a, xa);
        xb = fmaf(w1w, k1b + 2.f * (k2b + k3b) + k4b, xb);
        if (W == 0 && c == 0) *(float2*)xt_ptr = make_float2(xa, xb);
        xt_ptr += Bn * Dn;
        bcast(xa, xb);
    }

    if (W == 0 && c == 0) *(float2*)(xf_out + gs * Dn + ia) = make_float2(xa, xb);

    // ---- ldj: fold D-term (16/128 per lane), reduce wave then cross-wave ----
    ldjl = fmaf(0.125f, wbsum, ldjl);
    #pragma unroll
    for (int off = 1; off < 64; off <<= 1)
        ldjl += __shfl_xor(ldjl, off);
    if (L == 0) ldj_buf[W] = ldjl;
    __syncthreads();
    if (t == 0) ldj_out[gs] = ldj_buf[0] + ldj_buf[1];
}

extern "C" void kernel_launch(void* const* d_in, const int* in_sizes, int n_in,
                              void* d_out, int out_size, void* d_ws, size_t ws_size,
                              hipStream_t stream) {
    const float* x  = (const float*)d_in[0];
    const float* W1 = (const float*)d_in[1];
    const float* b1 = (const float*)d_in[2];
    const float* wt = (const float*)d_in[3];
    const float* W2 = (const float*)d_in[4];
    const float* b2 = (const float*)d_in[5];
    (void)in_sizes; (void)n_in; (void)out_size; (void)d_ws; (void)ws_size;
    ode_kernel<<<Bn, 128, 0, stream>>>(x, W1, b1, wt, W2, b2, (float*)d_out);
}

// Round 10
// 207.472 us; speedup vs baseline: 1.0533x; 1.0533x over previous
//
#include <hip/hip_runtime.h>
#include <stdint.h>

// ODE sampler (VP-SDE probability-flow, RK4, T=50) for B=2048, D=16, H=256.
// tr(J) analytic: tr = -0.5*beta*(D + sum_k (1-h_k^2)*c_k).
//
// R10 = R9 with the compile fix (cvt_pkrtz returns __fp16 vec -> bit_cast).
// R9/R10 vs R6 base (barrier-free, one wave/sample, 125us kernel):
//  - phase-1 dots on v_pk_fma_f16: u0/u1 packed in lo/hi halves, x broadcast
//    REPLICATED via SALU (8 v_readlane + s_pack_ll/hh) — tests the hypothesis
//    that v_dot2_f32_f16 is half-rate while pk_fma_f16 is full-rate.
//  - trace: h^2 via v_pk_mul_f16 + 2 fdot2 against f16-packed ck; constant
//    (0.25 + sum ck) folded into one fma. 13 -> 6 instrs.
//  - DPP reduce in 1-instr old=src form.
//  - beta/nhb/wb hoisted to per-step.
// Phase-2 kept on fdot2 (h-replication would double DS traffic).

typedef _Float16 f16x2 __attribute__((ext_vector_type(2)));

#if defined(__has_builtin)
#if __has_builtin(__builtin_amdgcn_fdot2)
#define HAVE_FDOT2 1
#endif
#endif

__device__ __forceinline__ float fdot2f(f16x2 a, f16x2 b, float c) {
#ifdef HAVE_FDOT2
    return __builtin_amdgcn_fdot2(a, b, c, false);
#else
    return fmaf((float)a.y, (float)b.y, fmaf((float)a.x, (float)b.x, c));
#endif
}

// v_cvt_pkrtz_f16_f32 returns __fp16 ext_vector(2); bit_cast to our f16x2.
__device__ __forceinline__ f16x2 pkrtz(float a, float b) {
    return __builtin_bit_cast(f16x2, __builtin_amdgcn_cvt_pkrtz(a, b));
}
__device__ __forceinline__ uint32_t pk(float a, float b) {
    return __builtin_bit_cast(uint32_t, __builtin_amdgcn_cvt_pkrtz(a, b));
}
__device__ __forceinline__ f16x2 upk(uint32_t u) {
    return __builtin_bit_cast(f16x2, u);
}

// DPP add, old=src single-instruction form (row-local perms only).
#define DPP_X1  0xB1    // quad_perm [1,0,3,2]  (^1)
#define DPP_X2  0x4E    // quad_perm [2,3,0,1]  (^2)
#define DPP_HM  0x141   // row_half_mirror      (^7 within 8)
template <int CTRL>
__device__ __forceinline__ float dpp_add(float x) {
    const int xi = __builtin_bit_cast(int, x);
    const int v  = __builtin_amdgcn_update_dpp(xi, xi, CTRL, 0xF, 0xF, false);
    return x + __builtin_bit_cast(float, v);
}

#define Bn 2048
#define Dn 16
#define Hn 256
#define Tn 50
#define CH 20            // dwords per 32-k h chunk: 16 data + 4 pad

__global__ __launch_bounds__(64) void ode_kernel(
    const float* __restrict__ x_in,   // [B][D]
    const float* __restrict__ W1,     // [D][H]
    const float* __restrict__ b1v,    // [H]
    const float* __restrict__ wtv,    // [H]
    const float* __restrict__ W2,     // [H][D]
    const float* __restrict__ b2v,    // [D]
    float* __restrict__ out)          // xf[B*D] | ldjf[B] | xt[T*B*D]
{
    __shared__ __align__(16) uint32_t h_lds[8 * CH];  // h, f16-pair packed

    const int L  = threadIdx.x;       // one wave per block = one sample
    const int g8 = L >> 3;            // i-pair group 0..7
    const int c  = L & 7;             // phase-2 k-chunk (32 k's)
    const int ia = 2 * g8, ib = ia + 1;
    const int k0 = 4 * L;             // phase-1: this lane's 4 hidden units
    const int gs = blockIdx.x;

    const float K2 = 2.88539008f;     // 2*log2(e): exp2(K2*u) = e^{2u}

    // ---- one-time init: weights packed to f16 registers ----
    // w1a[d] = K2*{W1[d][k0], W1[d][k0+1]}, w1b[d] = K2*{W1[d][k0+2], W1[d][k0+3]}
    f16x2 w1a[16], w1b[16];
    #pragma unroll
    for (int d = 0; d < 16; ++d) {
        w1a[d] = pkrtz(K2 * W1[d * Hn + k0],     K2 * W1[d * Hn + k0 + 1]);
        w1b[d] = pkrtz(K2 * W1[d * Hn + k0 + 2], K2 * W1[d * Hn + k0 + 3]);
    }
    float b1k[4], wtk[4], ckq[4];
    #pragma unroll
    for (int q = 0; q < 4; ++q) {
        const int k = k0 + q;
        b1k[q] = K2 * b1v[k];
        wtk[q] = K2 * wtv[k];
        float s = 0.f;
        #pragma unroll
        for (int ii = 0; ii < 16; ++ii)
            s = fmaf(W1[ii * Hn + k], W2[k * Dn + ii], s);
        ckq[q] = s;
    }
    const f16x2 ckp01 = pkrtz(ckq[0], ckq[1]);
    const f16x2 ckp23 = pkrtz(ckq[2], ckq[3]);
    const float Aconst = 0.25f + ((ckq[0] + ckq[1]) + (ckq[2] + ckq[3]));

    f16x2 w2a[16], w2b[16];           // [m] = {W2[32c+2m][i*], W2[32c+2m+1][i*]}
    #pragma unroll
    for (int m = 0; m < 16; ++m) {
        const int kk = 32 * c + 2 * m;
        w2a[m] = pkrtz(W2[kk * Dn + ia], W2[(kk + 1) * Dn + ia]);
        w2b[m] = pkrtz(W2[kk * Dn + ib], W2[(kk + 1) * Dn + ib]);
    }
    const float b2a = b2v[ia], b2b = b2v[ib];

    float xa = x_in[gs * Dn + ia];
    float xb = x_in[gs * Dn + ib];
    float ldjl = 0.f;

    float* xf_out  = out;
    float* ldj_out = out + (size_t)Bn * Dn;
    float* xt_ptr  = out + (size_t)Bn * Dn + Bn + gs * Dn + ia;

    if (c == 0) *(float2*)xt_ptr = make_float2(xa, xb);   // xt[0]
    xt_ptr += Bn * Dn;

    const int hwidx = CH * (L >> 3) + 2 * (L & 7);        // h write slot (b64)

    // x-broadcast: 8 readlanes (pairs) -> SALU-replicated 16 uniform f16x2
    uint32_t rep[16];
    auto bcast = [&](float ea, float eb) {
        const uint32_t vpk = pk(ea, eb);      // lane 8j holds (x_2j, x_2j+1)
        #pragma unroll
        for (int j = 0; j < 8; ++j) {
            const uint32_t s = __builtin_amdgcn_readlane(vpk, 8 * j);  // SGPR
            rep[2 * j]     = (s & 0xffffu) | (s << 16);        // s_pack_ll
            rep[2 * j + 1] = (s >> 16) | (s & 0xffff0000u);    // s_pack_hh
        }
    };

    auto Feval = [&](float xeva, float xevb, float tt, float nhb, float wb,
                     float& dxa, float& dxb) {
        // ---- phase 1: u0..u3 via packed f16 FMA (u-pairs in lo/hi) ----
        f16x2 a01 = pkrtz(fmaf(tt, wtk[0], b1k[0]), fmaf(tt, wtk[1], b1k[1]));
        f16x2 a23 = pkrtz(fmaf(tt, wtk[2], b1k[2]), fmaf(tt, wtk[3], b1k[3]));
        #pragma unroll
        for (int d = 0; d < 16; ++d) {
            const f16x2 xr = upk(rep[d]);     // (x_d, x_d), SGPR source
            a01 = __builtin_elementwise_fma(xr, w1a[d], a01);   // v_pk_fma_f16
            a23 = __builtin_elementwise_fma(xr, w1b[d], a23);
        }
        const float u0 = (float)a01.x, u1 = (float)a01.y;
        const float u2 = (float)a23.x, u3 = (float)a23.y;
        // prescaled: exp2(u)=e^{2u_true}; tanh = 1 - 2/(E+1), saturation exact
        const float h0 = fmaf(-2.f, __builtin_amdgcn_rcpf(__builtin_amdgcn_exp2f(u0) + 1.f), 1.f);
        const float h1 = fmaf(-2.f, __builtin_amdgcn_rcpf(__builtin_amdgcn_exp2f(u1) + 1.f), 1.f);
        const float h2 = fmaf(-2.f, __builtin_amdgcn_rcpf(__builtin_amdgcn_exp2f(u2) + 1.f), 1.f);
        const float h3 = fmaf(-2.f, __builtin_amdgcn_rcpf(__builtin_amdgcn_exp2f(u3) + 1.f), 1.f);
        const f16x2 hp01 = pkrtz(h0, h1);
        const f16x2 hp23 = pkrtz(h2, h3);
        *(uint2*)&h_lds[hwidx] = make_uint2(__builtin_bit_cast(uint32_t, hp01),
                                            __builtin_bit_cast(uint32_t, hp23));

        // trace: P = sum h^2*ck (pk_mul + fdot2); ldj += wb*(A - P)
        const f16x2 q01 = hp01 * hp01;        // v_pk_mul_f16
        const f16x2 q23 = hp23 * hp23;
        const float P = fdot2f(q01, ckp01, fdot2f(q23, ckp23, 0.f));
        ldjl = fmaf(wb, Aconst - P, ldjl);

        asm volatile("" ::: "memory");        // keep h write above the reads

        // ---- phase 2: score for (ia, ib) over k-chunk c (fdot2) ----
        float sa0 = 0.f, sa1 = 0.f, sb0 = 0.f, sb1 = 0.f;
        #pragma unroll
        for (int mq = 0; mq < 4; ++mq) {
            const uint4 hv = *(const uint4*)&h_lds[CH * c + 4 * mq];
            const f16x2 p0 = upk(hv.x), p1 = upk(hv.y), p2 = upk(hv.z), p3 = upk(hv.w);
            sa0 = fdot2f(p0, w2a[4 * mq + 0], sa0);
            sb0 = fdot2f(p0, w2b[4 * mq + 0], sb0);
            sa1 = fdot2f(p1, w2a[4 * mq + 1], sa1);
            sb1 = fdot2f(p1, w2b[4 * mq + 1], sb1);
            sa0 = fdot2f(p2, w2a[4 * mq + 2], sa0);
            sb0 = fdot2f(p2, w2b[4 * mq + 2], sb0);
            sa1 = fdot2f(p3, w2a[4 * mq + 3], sa1);
            sb1 = fdot2f(p3, w2b[4 * mq + 3], sb1);
        }
        float sca = sa0 + sa1, scb = sb0 + sb1;
        sca = dpp_add<DPP_X1>(sca);  scb = dpp_add<DPP_X1>(scb);
        sca = dpp_add<DPP_X2>(sca);  scb = dpp_add<DPP_X2>(scb);
        sca = dpp_add<DPP_HM>(sca);  scb = dpp_add<DPP_HM>(scb);
        sca += b2a;  scb += b2b;

        dxa = nhb * (xeva + sca);
        dxb = nhb * (xevb + scb);
    };

    const float t_lo = 1e-3f;
    const float dt   = (1.0f - 1e-3f) / (float)(Tn - 1);
    const float hh   = dt;
    const float w1w  = hh * (1.f / 6.f);
    const float w2w  = hh * (2.f / 6.f);

    bcast(xa, xb);
    for (int j = 0; j < Tn - 1; ++j) {
        const float t0 = fmaf((float)j, dt, t_lo);
        const float tm = t0 + 0.5f * hh;
        const float t1 = t0 + hh;
        // per-step hoisted beta factors: nhb = -0.5*(0.1 + 19.9 t)
        const float nhb0 = fmaf(t0, -9.95f, -0.05f);
        const float nhbm = fmaf(tm, -9.95f, -0.05f);
        const float nhb1 = fmaf(t1, -9.95f, -0.05f);
        const float wbA  = w1w * nhb0;
        const float wbB  = w2w * nhbm;
        const float wbC  = w1w * nhb1;

        float k1a, k1b, k2a, k2b, k3a, k3b, k4a, k4b;
        Feval(xa, xb, t0, nhb0, wbA, k1a, k1b);
        const float e2a = fmaf(0.5f * hh, k1a, xa);
        const float e2b = fmaf(0.5f * hh, k1b, xb);
        bcast(e2a, e2b);
        Feval(e2a, e2b, tm, nhbm, wbB, k2a, k2b);
        const float e3a = fmaf(0.5f * hh, k2a, xa);
        const float e3b = fmaf(0.5f * hh, k2b, xb);
        bcast(e3a, e3b);
        Feval(e3a, e3b, tm, nhbm, wbB, k3a, k3b);
        const float e4a = fmaf(hh, k3a, xa);
        const float e4b = fmaf(hh, k3b, xb);
        bcast(e4a, e4b);
        Feval(e4a, e4b, t1, nhb1, wbC, k4a, k4b);

        xa = fmaf(w1w, k1a + 2.f * (k2a + k3a) + k4a, xa);
        xb = fmaf(w1w, k1b + 2.f * (k2b + k3b) + k4b, xb);
        if (c == 0) *(float2*)xt_ptr = make_float2(xa, xb);
        xt_ptr += Bn * Dn;
        bcast(xa, xb);
    }

    if (c == 0) *(float2*)(xf_out + gs * Dn + ia) = make_float2(xa, xb);

    // ldj: one-time full-wave butterfly (constants already folded per Feval)
    #pragma unroll
    for (int off = 1; off < 64; off <<= 1)
        ldjl += __shfl_xor(ldjl, off);
    if (L == 0) ldj_out[gs] = ldjl;
}

extern "C" void kernel_launch(void* const* d_in, const int* in_sizes, int n_in,
                              void* d_out, int out_size, void* d_ws, size_t ws_size,
                              hipStream_t stream) {
    const float* x  = (const float*)d_in[0];
    const float* W1 = (const float*)d_in[1];
    const float* b1 = (const float*)d_in[2];
    const float* wt = (const float*)d_in[3];
    const float* W2 = (const float*)d_in[4];
    const float* b2 = (const float*)d_in[5];
    (void)in_sizes; (void)n_in; (void)out_size; (void)d_ws; (void)ws_size;
    ode_kernel<<<Bn, 64, 0, stream>>>(x, W1, b1, wt, W2, b2, (float*)d_out);
}

// Round 11
// 175.486 us; speedup vs baseline: 1.2453x; 1.1823x over previous
//
#include <hip/hip_runtime.h>
#include <stdint.h>

// ODE sampler (VP-SDE probability-flow, RK4, T=50) for B=2048, D=16, H=256.
// tr(J) analytic: tr = -0.5*beta*(D + sum_k (1-h_k^2)*c_k).
//
// R11 = R6 (best: 125us kernel / 171.6 bench) + audited micro-trims only:
//  - trace: reuse packed h pairs -> v_pk_mul_f16 h^2 + 2 fdot2 vs f16 ck;
//    ldj += wb*(A - P), A = 0.25 + sum ck  (16 -> 8 instrs, algebra-equal)
//  - beta/nhb/wb hoisted to per-step scalars (-4 instr/Feval)
//  - DPP adds in old=src fusable form
// Established invariants (R4-R10): 64 fdot2/sample/lane is mapping-invariant;
// barrier-free 1-wave/sample (2048 waves) is the TLP max; every barrier
// variant (R2/R5/R8), pk_fma_f32 (R7), pk_fma_f16 (R10) lost to R6.

typedef _Float16 f16x2 __attribute__((ext_vector_type(2)));

#if defined(__has_builtin)
#if __has_builtin(__builtin_amdgcn_fdot2)
#define HAVE_FDOT2 1
#endif
#endif

__device__ __forceinline__ float fdot2f(f16x2 a, f16x2 b, float c) {
#ifdef HAVE_FDOT2
    return __builtin_amdgcn_fdot2(a, b, c, false);
#else
    return fmaf((float)a.y, (float)b.y, fmaf((float)a.x, (float)b.x, c));
#endif
}

// v_cvt_pkrtz_f16_f32 returns __fp16 ext_vector(2); bit_cast to our f16x2.
__device__ __forceinline__ f16x2 pkrtz(float a, float b) {
    return __builtin_bit_cast(f16x2, __builtin_amdgcn_cvt_pkrtz(a, b));
}
__device__ __forceinline__ uint32_t pk(float a, float b) {
    return __builtin_bit_cast(uint32_t, __builtin_amdgcn_cvt_pkrtz(a, b));
}
__device__ __forceinline__ f16x2 upk(uint32_t u) {
    return __builtin_bit_cast(f16x2, u);
}

// DPP add, old=src form (fusable to v_add_f32_dpp; row-local perms only).
#define DPP_X1  0xB1    // quad_perm [1,0,3,2]  (^1)
#define DPP_X2  0x4E    // quad_perm [2,3,0,1]  (^2)
#define DPP_HM  0x141   // row_half_mirror      (^7 within 8)
template <int CTRL>
__device__ __forceinline__ float dpp_add(float x) {
    const int xi = __builtin_bit_cast(int, x);
    const int v  = __builtin_amdgcn_update_dpp(xi, xi, CTRL, 0xF, 0xF, false);
    return x + __builtin_bit_cast(float, v);
}

#define Bn 2048
#define Dn 16
#define Hn 256
#define Tn 50
#define CH 20            // dwords per 32-k h chunk: 16 data + 4 pad

__global__ __launch_bounds__(64) void ode_kernel(
    const float* __restrict__ x_in,   // [B][D]
    const float* __restrict__ W1,     // [D][H]
    const float* __restrict__ b1v,    // [H]
    const float* __restrict__ wtv,    // [H]
    const float* __restrict__ W2,     // [H][D]
    const float* __restrict__ b2v,    // [D]
    float* __restrict__ out)          // xf[B*D] | ldjf[B] | xt[T*B*D]
{
    __shared__ __align__(16) uint32_t h_lds[8 * CH];  // h, f16-pair packed

    const int L  = threadIdx.x;       // one wave per block = one sample
    const int g8 = L >> 3;            // i-pair group 0..7
    const int c  = L & 7;             // phase-2 k-chunk (32 k's)
    const int ia = 2 * g8, ib = ia + 1;
    const int k0 = 4 * L;             // phase-1: this lane's 4 hidden units
    const int gs = blockIdx.x;

    const float K2 = 2.88539008f;     // 2*log2(e): exp2(K2*u) = e^{2u}

    // ---- one-time init: weights packed to f16 registers (R6 layout) ----
    f16x2 w1p[4][8];                  // [q][j] = K2*{W1[2j][k0+q], W1[2j+1][k0+q]}
    float b1k[4], wtk[4], ckq[4];
    #pragma unroll
    for (int q = 0; q < 4; ++q) {
        const int k = k0 + q;
        #pragma unroll
        for (int j = 0; j < 8; ++j)
            w1p[q][j] = pkrtz(K2 * W1[(2 * j) * Hn + k],
                              K2 * W1[(2 * j + 1) * Hn + k]);
        b1k[q] = K2 * b1v[k];
        wtk[q] = K2 * wtv[k];
        float s = 0.f;                // c_k from original f32 weights
        #pragma unroll
        for (int ii = 0; ii < 16; ++ii)
            s = fmaf(W1[ii * Hn + k], W2[k * Dn + ii], s);
        ckq[q] = s;
    }
    const f16x2 ckp01 = pkrtz(ckq[0], ckq[1]);
    const f16x2 ckp23 = pkrtz(ckq[2], ckq[3]);
    const float Aconst = 0.25f + ((ckq[0] + ckq[1]) + (ckq[2] + ckq[3]));

    f16x2 w2a[16], w2b[16];           // [m] = {W2[32c+2m][i*], W2[32c+2m+1][i*]}
    #pragma unroll
    for (int m = 0; m < 16; ++m) {
        const int kk = 32 * c + 2 * m;
        w2a[m] = pkrtz(W2[kk * Dn + ia], W2[(kk + 1) * Dn + ia]);
        w2b[m] = pkrtz(W2[kk * Dn + ib], W2[(kk + 1) * Dn + ib]);
    }
    const float b2a = b2v[ia], b2b = b2v[ib];

    float xa = x_in[gs * Dn + ia];
    float xb = x_in[gs * Dn + ib];
    float ldjl = 0.f;

    float* xf_out  = out;
    float* ldj_out = out + (size_t)Bn * Dn;
    float* xt_ptr  = out + (size_t)Bn * Dn + Bn + gs * Dn + ia;

    if (c == 0) *(float2*)xt_ptr = make_float2(xa, xb);   // xt[0]
    xt_ptr += Bn * Dn;

    const int hwidx = CH * (L >> 3) + 2 * (L & 7);        // h write slot (b64)

    // x-broadcast: 8 readlanes -> wave-uniform packed f16 pairs (R6 form)
    uint32_t se0, se1, se2, se3, se4, se5, se6, se7;
    auto bcast = [&](float ea, float eb) {
        const uint32_t vpk = pk(ea, eb);      // lane 8j holds (x_2j, x_2j+1)
        se0 = __builtin_amdgcn_readlane(vpk,  0);
        se1 = __builtin_amdgcn_readlane(vpk,  8);
        se2 = __builtin_amdgcn_readlane(vpk, 16);
        se3 = __builtin_amdgcn_readlane(vpk, 24);
        se4 = __builtin_amdgcn_readlane(vpk, 32);
        se5 = __builtin_amdgcn_readlane(vpk, 40);
        se6 = __builtin_amdgcn_readlane(vpk, 48);
        se7 = __builtin_amdgcn_readlane(vpk, 56);
    };

    auto Feval = [&](float xeva, float xevb, float tt, float nhb, float wb,
                     float& dxa, float& dxb) {
        // ---- phase 1: this lane's 4 hidden units (32 fdot2, R6 form) ----
        const f16x2 xp[8] = { upk(se0), upk(se1), upk(se2), upk(se3),
                              upk(se4), upk(se5), upk(se6), upk(se7) };
        float u0 = fmaf(tt, wtk[0], b1k[0]);
        float u1 = fmaf(tt, wtk[1], b1k[1]);
        float u2 = fmaf(tt, wtk[2], b1k[2]);
        float u3 = fmaf(tt, wtk[3], b1k[3]);
        #pragma unroll
        for (int j = 0; j < 8; ++j) {
            u0 = fdot2f(xp[j], w1p[0][j], u0);
            u1 = fdot2f(xp[j], w1p[1][j], u1);
            u2 = fdot2f(xp[j], w1p[2][j], u2);
            u3 = fdot2f(xp[j], w1p[3][j], u3);
        }
        // prescaled: exp2(u)=e^{2u_true}; tanh = 1 - 2/(E+1), saturation exact
        const float h0 = fmaf(-2.f, __builtin_amdgcn_rcpf(__builtin_amdgcn_exp2f(u0) + 1.f), 1.f);
        const float h1 = fmaf(-2.f, __builtin_amdgcn_rcpf(__builtin_amdgcn_exp2f(u1) + 1.f), 1.f);
        const float h2 = fmaf(-2.f, __builtin_amdgcn_rcpf(__builtin_amdgcn_exp2f(u2) + 1.f), 1.f);
        const float h3 = fmaf(-2.f, __builtin_amdgcn_rcpf(__builtin_amdgcn_exp2f(u3) + 1.f), 1.f);
        const f16x2 hp01 = pkrtz(h0, h1);
        const f16x2 hp23 = pkrtz(h2, h3);
        *(uint2*)&h_lds[hwidx] = make_uint2(__builtin_bit_cast(uint32_t, hp01),
                                            __builtin_bit_cast(uint32_t, hp23));

        // trace (trimmed): P = sum h^2*ck via pk_mul + 2 fdot2;
        // ldj += wb*(A - P) == wb*0.25 + wb*sum(1-h^2)ck   [algebra-equal R6]
        const f16x2 q01 = hp01 * hp01;        // v_pk_mul_f16
        const f16x2 q23 = hp23 * hp23;
        const float P = fdot2f(q01, ckp01, fdot2f(q23, ckp23, 0.f));
        ldjl = fmaf(wb, Aconst - P, ldjl);

        asm volatile("" ::: "memory");        // keep h write above the reads

        // ---- phase 2: score for (ia, ib) over k-chunk c (32 fdot2) ----
        float sa0 = 0.f, sa1 = 0.f, sb0 = 0.f, sb1 = 0.f;
        #pragma unroll
        for (int mq = 0; mq < 4; ++mq) {
            const uint4 hv = *(const uint4*)&h_lds[CH * c + 4 * mq];
            const f16x2 p0 = upk(hv.x), p1 = upk(hv.y), p2 = upk(hv.z), p3 = upk(hv.w);
            sa0 = fdot2f(p0, w2a[4 * mq + 0], sa0);
            sb0 = fdot2f(p0, w2b[4 * mq + 0], sb0);
            sa1 = fdot2f(p1, w2a[4 * mq + 1], sa1);
            sb1 = fdot2f(p1, w2b[4 * mq + 1], sb1);
            sa0 = fdot2f(p2, w2a[4 * mq + 2], sa0);
            sb0 = fdot2f(p2, w2b[4 * mq + 2], sb0);
            sa1 = fdot2f(p3, w2a[4 * mq + 3], sa1);
            sb1 = fdot2f(p3, w2b[4 * mq + 3], sb1);
        }
        float sca = sa0 + sa1, scb = sb0 + sb1;
        sca = dpp_add<DPP_X1>(sca);  scb = dpp_add<DPP_X1>(scb);
        sca = dpp_add<DPP_X2>(sca);  scb = dpp_add<DPP_X2>(scb);
        sca = dpp_add<DPP_HM>(sca);  scb = dpp_add<DPP_HM>(scb);
        sca += b2a;  scb += b2b;

        dxa = nhb * (xeva + sca);
        dxb = nhb * (xevb + scb);
    };

    const float t_lo = 1e-3f;
    const float dt   = (1.0f - 1e-3f) / (float)(Tn - 1);
    const float hh   = dt;
    const float w1w  = hh * (1.f / 6.f);
    const float w2w  = hh * (2.f / 6.f);

    bcast(xa, xb);
    for (int j = 0; j < Tn - 1; ++j) {
        const float t0 = fmaf((float)j, dt, t_lo);
        const float tm = t0 + 0.5f * hh;
        const float t1 = t0 + hh;
        // hoisted beta factors: nhb = -0.5*(0.1 + 19.9 t)
        const float nhb0 = fmaf(t0, -9.95f, -0.05f);
        const float nhbm = fmaf(tm, -9.95f, -0.05f);
        const float nhb1 = fmaf(t1, -9.95f, -0.05f);
        const float wbA  = w1w * nhb0;
        const float wbB  = w2w * nhbm;
        const float wbC  = w1w * nhb1;

        float k1a, k1b, k2a, k2b, k3a, k3b, k4a, k4b;
        Feval(xa, xb, t0, nhb0, wbA, k1a, k1b);
        const float e2a = fmaf(0.5f * hh, k1a, xa);
        const float e2b = fmaf(0.5f * hh, k1b, xb);
        bcast(e2a, e2b);
        Feval(e2a, e2b, tm, nhbm, wbB, k2a, k2b);
        const float e3a = fmaf(0.5f * hh, k2a, xa);
        const float e3b = fmaf(0.5f * hh, k2b, xb);
        bcast(e3a, e3b);
        Feval(e3a, e3b, tm, nhbm, wbB, k3a, k3b);
        const float e4a = fmaf(hh, k3a, xa);
        const float e4b = fmaf(hh, k3b, xb);
        bcast(e4a, e4b);
        Feval(e4a, e4b, t1, nhb1, wbC, k4a, k4b);

        xa = fmaf(w1w, k1a + 2.f * (k2a + k3a) + k4a, xa);
        xb = fmaf(w1w, k1b + 2.f * (k2b + k3b) + k4b, xb);
        if (c == 0) *(float2*)xt_ptr = make_float2(xa, xb);
        xt_ptr += Bn * Dn;
        bcast(xa, xb);
    }

    if (c == 0) *(float2*)(xf_out + gs * Dn + ia) = make_float2(xa, xb);

    // ldj: one-time full-wave butterfly (constants folded per Feval)
    #pragma unroll
    for (int off = 1; off < 64; off <<= 1)
        ldjl += __shfl_xor(ldjl, off);
    if (L == 0) ldj_out[gs] = ldjl;
}

extern "C" void kernel_launch(void* const* d_in, const int* in_sizes, int n_in,
                              void* d_out, int out_size, void* d_ws, size_t ws_size,
                              hipStream_t stream) {
    const float* x  = (const float*)d_in[0];
    const float* W1 = (const float*)d_in[1];
    const float* b1 = (const float*)d_in[2];
    const float* wt = (const float*)d_in[3];
    const float* W2 = (const float*)d_in[4];
    const float* b2 = (const float*)d_in[5];
    (void)in_sizes; (void)n_in; (void)out_size; (void)d_ws; (void)ws_size;
    ode_kernel<<<Bn, 64, 0, stream>>>(x, W1, b1, wt, W2, b2, (float*)d_out);
}